// Round 9
// baseline (61.675 us; speedup 1.0000x reference)
//
#include <hip/hip_runtime.h>
#include <math.h>

// Problem: S=4096, B=16, H=1024
//   energies[b,s] = hidden[b,:] . (W @ enc[s,b,:] + b_attn)
//   out[b,0,s]    = softmax_s(energies[b,s])
// Reassociated: energies[b,s] = v[b,:] . enc[s,b,:] (+ const_b, cancels in
// softmax shift-invariance), v = hidden @ W.  b_attn never read.
//
// History: coop-API fusion refuted (R4: spills). nontemporal refuted (R2).
// B@8waves/SIMD refuted (R6). low-wave GEMV refuted (R8). B is pinned at the
// 6.3-6.4 TB/s read ceiling (R5 strided-reg == R7 contiguous-LDS).
// R9: ONE kernel, spin-barrier fused. 512 blocks x 64KB LDS -> exactly 2
// blocks/CU -> grid == device capacity -> co-residency structurally
// guaranteed -> ticket barriers deadlock-free (G16: device-scope atomics +
// threadfence release/acquire). Energies stay in acc[4][4] registers
// (static indexing only) from stream to final write. Fallback = R7 path.

#define SS 4096
#define BB 16
#define HH 1024
#define BNB 512        // fused grid: 512 blocks = 2/CU x 256 CU exactly
#define BNT 512        // 8 waves
#define TILES 4        // 4 groups of 32 consecutive pairs per block

typedef float f4 __attribute__((ext_vector_type(4)));

__device__ __forceinline__ unsigned flipf(float f) {
    unsigned u = __float_as_uint(f);
    return (u & 0x80000000u) ? ~u : (u | 0x80000000u);
}
__device__ __forceinline__ float unflipf(unsigned u) {
    return __uint_as_float((u & 0x80000000u) ? (u & 0x7fffffffu) : ~u);
}

// Deadlock-free only because grid == resident capacity (2/CU enforced by LDS).
__device__ __forceinline__ void grid_barrier(unsigned* cnt) {
    __syncthreads();                 // waves' prior stores drained (vmcnt) pre-barrier
    __threadfence();                 // release: write back local L2
    if (threadIdx.x == 0) {
        __hip_atomic_fetch_add(cnt, 1u, __ATOMIC_ACQ_REL, __HIP_MEMORY_SCOPE_AGENT);
        while (__hip_atomic_load(cnt, __ATOMIC_ACQUIRE, __HIP_MEMORY_SCOPE_AGENT)
               < (unsigned)BNB)
            __builtin_amdgcn_s_sleep(2);
    }
    __syncthreads();
    __threadfence();                 // acquire: invalidate local L2 -> fresh reads
}

// ---------------- PRIMARY: fully fused kernel ------------------------------
// ws layout: ctrl[64] unsigned (bar0,bar1,bar2 @0..2; maxbits @16..31;
// sums @32..47) then v[16384] floats.
__global__ void __launch_bounds__(BNT, 4)
fused_kernel(const float* __restrict__ hidden,
             const float* __restrict__ enc,
             const float* __restrict__ W,
             float* __restrict__ out,
             unsigned* __restrict__ ctrl,
             float* __restrict__ v) {
    __shared__ f4 vlds[BB * HH / 4];          // 64 KB (aliased as red[] in P1)
    __shared__ unsigned lds_max[BB];
    __shared__ float    lds_sum[BB];
    float* red = (float*)vlds;
    int tid = threadIdx.x;

    // ---- P1: GEMV v[b,h] = sum_k hidden[b,k]*W[k,h] ----------------------
    // 512 blocks x 32 h-outputs: b = bid>>5, hbase = (bid&31)*32.
    // threads = kc(16, 64-k chunks) x ho(32): 4096 waves total (A1-proven).
    {
        int b_    = blockIdx.x >> 5;
        int hbase = (blockIdx.x & 31) << 5;
        int kc    = tid >> 5;
        int ho    = tid & 31;
        const float* hrow = hidden + b_ * HH + kc * 64;
        const float* Wp   = W + (size_t)(kc * 64) * HH + hbase + ho;
        float a0 = 0.f, a1 = 0.f, a2 = 0.f, a3 = 0.f;
        #pragma unroll 4
        for (int k = 0; k < 64; k += 4) {
            a0 += hrow[k + 0] * Wp[(k + 0) * HH];
            a1 += hrow[k + 1] * Wp[(k + 1) * HH];
            a2 += hrow[k + 2] * Wp[(k + 2) * HH];
            a3 += hrow[k + 3] * Wp[(k + 3) * HH];
        }
        red[tid] = (a0 + a1) + (a2 + a3);
        __syncthreads();
        if (tid < 32) {
            float s = 0.f;
            #pragma unroll
            for (int kc2 = 0; kc2 < 16; ++kc2) s += red[kc2 * 32 + tid];
            v[b_ * HH + hbase + tid] = s;
        }
    }
    grid_barrier(&ctrl[0]);

    // ---- P2: stage v -> LDS, stream enc, energies to registers -----------
    {
        const f4* vg = (const f4*)v;
        #pragma unroll
        for (int it = 0; it < (BB * HH / 4) / BNT; ++it)
            vlds[it * BNT + tid] = vg[it * BNT + tid];
    }
    __syncthreads();

    int lane = tid & 63;
    int wi   = tid >> 6;
    float acc[TILES][4];
    #pragma unroll
    for (int t = 0; t < TILES; ++t) {
        int g  = t * BNB + blockIdx.x;
        int p0 = g * 32 + wi * 4;
        #pragma unroll
        for (int j = 0; j < 4; ++j) {
            int p  = p0 + j;
            int b_ = p & (BB - 1);
            const f4* e4 = (const f4*)(enc + (size_t)p * HH);
            f4 a0 = e4[0 * 64 + lane];
            f4 a1 = e4[1 * 64 + lane];
            f4 a2 = e4[2 * 64 + lane];
            f4 a3 = e4[3 * 64 + lane];
            f4 w0 = vlds[b_ * 256 + 0 * 64 + lane];
            f4 w1 = vlds[b_ * 256 + 1 * 64 + lane];
            f4 w2 = vlds[b_ * 256 + 2 * 64 + lane];
            f4 w3 = vlds[b_ * 256 + 3 * 64 + lane];
            f4 pr = a0 * w0 + a1 * w1 + a2 * w2 + a3 * w3;
            acc[t][j] = (pr.x + pr.y) + (pr.z + pr.w);
        }
        #pragma unroll
        for (int j = 0; j < 4; ++j) {
            #pragma unroll
            for (int off = 32; off; off >>= 1)
                acc[t][j] += __shfl_xor(acc[t][j], off, 64);
        }
    }

    // ---- P3: per-b max: LDS pre-reduce -> 16-slot global atomicMax -------
    if (tid < BB) lds_max[tid] = 0u;          // flip-code floor
    __syncthreads();
    if (lane == 0) {
        #pragma unroll
        for (int j = 0; j < 4; ++j) {
            float m = fmaxf(fmaxf(acc[0][j], acc[1][j]),
                            fmaxf(acc[2][j], acc[3][j]));
            atomicMax(&lds_max[(wi * 4 + j) & (BB - 1)], flipf(m));
        }
    }
    __syncthreads();
    if (tid < BB) atomicMax(&ctrl[16 + tid], lds_max[tid]);
    grid_barrier(&ctrl[1]);

    // ---- P4: exp + per-b sum: LDS pre-reduce -> global atomicAdd ---------
    float mb[4];
    #pragma unroll
    for (int j = 0; j < 4; ++j)
        mb[j] = unflipf(ctrl[16 + ((wi * 4 + j) & (BB - 1))]);
    if (tid < BB) lds_sum[tid] = 0.f;
    __syncthreads();
    #pragma unroll
    for (int t = 0; t < TILES; ++t)
        #pragma unroll
        for (int j = 0; j < 4; ++j)
            acc[t][j] = expf(acc[t][j] - mb[j]);
    if (lane == 0) {
        #pragma unroll
        for (int j = 0; j < 4; ++j) {
            float s = ((acc[0][j] + acc[1][j]) + (acc[2][j] + acc[3][j]));
            atomicAdd(&lds_sum[(wi * 4 + j) & (BB - 1)], s);
        }
    }
    __syncthreads();
    if (tid < BB) atomicAdd((float*)&ctrl[32 + tid], lds_sum[tid]);
    grid_barrier(&ctrl[2]);

    // ---- P5: normalize + write (only traffic: 256 KB out) ----------------
    float inv[4];
    #pragma unroll
    for (int j = 0; j < 4; ++j)
        inv[j] = 1.0f / ((float*)&ctrl[32])[(wi * 4 + j) & (BB - 1)];
    if (lane == 0) {
        #pragma unroll
        for (int t = 0; t < TILES; ++t) {
            int p0 = (t * BNB + blockIdx.x) * 32 + wi * 4;
            #pragma unroll
            for (int j = 0; j < 4; ++j) {
                int p = p0 + j;
                out[(p & (BB - 1)) * SS + (p >> 4)] = acc[t][j] * inv[j];
            }
        }
    }
}

// ---------------- FALLBACK: R7's proven 4-kernel path (56.7us) -------------
#define KC 16
#define KLEN (HH / KC)

__global__ void __launch_bounds__(256)
gemv_partial_kernel(const float* __restrict__ hidden,
                    const float* __restrict__ W,
                    float* __restrict__ partial) {
    int blk = blockIdx.x;
    int kc  = blk >> 6;
    int rb  = blk & 63;
    int b   = rb >> 2;
    int h   = ((rb & 3) << 8) | threadIdx.x;
    const float* hrow = hidden + b * HH + kc * KLEN;
    const float* Wp   = W + (size_t)(kc * KLEN) * HH + h;
    float a0 = 0.f, a1 = 0.f, a2 = 0.f, a3 = 0.f;
    #pragma unroll 4
    for (int k = 0; k < KLEN; k += 4) {
        a0 += hrow[k + 0] * Wp[(k + 0) * HH];
        a1 += hrow[k + 1] * Wp[(k + 1) * HH];
        a2 += hrow[k + 2] * Wp[(k + 2) * HH];
        a3 += hrow[k + 3] * Wp[(k + 3) * HH];
    }
    partial[kc * (BB * HH) + b * HH + h] = (a0 + a1) + (a2 + a3);
}

__global__ void __launch_bounds__(256)
gemv_reduce_kernel(const float* __restrict__ partial,
                   float* __restrict__ v) {
    int i = blockIdx.x * 256 + threadIdx.x;
    float s = 0.f;
    #pragma unroll
    for (int kc = 0; kc < KC; ++kc) s += partial[kc * (BB * HH) + i];
    v[i] = s;
}

__global__ void __launch_bounds__(BNT, 4)
energies_kernel(const float* __restrict__ enc,
                const float* __restrict__ v,
                float* __restrict__ out) {
    __shared__ f4 vlds[BB * HH / 4];
    int tid = threadIdx.x;
    const f4* vg = (const f4*)v;
    #pragma unroll
    for (int it = 0; it < (BB * HH / 4) / BNT; ++it)
        vlds[it * BNT + tid] = vg[it * BNT + tid];
    __syncthreads();
    int lane = tid & 63;
    int wi   = tid >> 6;
    for (int t = 0; t < TILES; ++t) {
        int g  = t * BNB + blockIdx.x;
        int p0 = g * 32 + wi * 4;
        float acc[4];
        #pragma unroll
        for (int j = 0; j < 4; ++j) {
            int p = p0 + j;
            int b = p & (BB - 1);
            const f4* e4 = (const f4*)(enc + (size_t)p * HH);
            f4 a0 = e4[0 * 64 + lane];
            f4 a1 = e4[1 * 64 + lane];
            f4 a2 = e4[2 * 64 + lane];
            f4 a3 = e4[3 * 64 + lane];
            f4 w0 = vlds[b * 256 + 0 * 64 + lane];
            f4 w1 = vlds[b * 256 + 1 * 64 + lane];
            f4 w2 = vlds[b * 256 + 2 * 64 + lane];
            f4 w3 = vlds[b * 256 + 3 * 64 + lane];
            f4 pr = a0 * w0 + a1 * w1 + a2 * w2 + a3 * w3;
            acc[j] = (pr.x + pr.y) + (pr.z + pr.w);
        }
        #pragma unroll
        for (int j = 0; j < 4; ++j) {
            #pragma unroll
            for (int off = 32; off; off >>= 1)
                acc[j] += __shfl_xor(acc[j], off, 64);
        }
        if (lane == 0) {
            #pragma unroll
            for (int j = 0; j < 4; ++j) {
                int p = p0 + j;
                out[(p & (BB - 1)) * SS + (p >> 4)] = acc[j];
            }
        }
    }
}

__global__ void __launch_bounds__(256)
softmax_kernel(float* __restrict__ out) {
    int b = blockIdx.x;
    float* row = out + b * SS;
    int t = threadIdx.x;
    float vals[16];
    float m = -INFINITY;
    #pragma unroll
    for (int i = 0; i < 16; ++i) {
        vals[i] = row[t + i * 256];
        m = fmaxf(m, vals[i]);
    }
    #pragma unroll
    for (int off = 32; off; off >>= 1) m = fmaxf(m, __shfl_xor(m, off, 64));
    __shared__ float redm[4];
    __shared__ float reds[4];
    int wid = t >> 6;
    if ((t & 63) == 0) redm[wid] = m;
    __syncthreads();
    m = fmaxf(fmaxf(redm[0], redm[1]), fmaxf(redm[2], redm[3]));
    float sum = 0.f;
    #pragma unroll
    for (int i = 0; i < 16; ++i) {
        vals[i] = expf(vals[i] - m);
        sum += vals[i];
    }
    #pragma unroll
    for (int off = 32; off; off >>= 1) sum += __shfl_xor(sum, off, 64);
    if ((t & 63) == 0) reds[wid] = sum;
    __syncthreads();
    sum = reds[0] + reds[1] + reds[2] + reds[3];
    float inv = 1.0f / sum;
    #pragma unroll
    for (int i = 0; i < 16; ++i) row[t + i * 256] = vals[i] * inv;
}

extern "C" void kernel_launch(void* const* d_in, const int* in_sizes, int n_in,
                              void* d_out, int out_size, void* d_ws, size_t ws_size,
                              hipStream_t stream) {
    const float* hidden = (const float*)d_in[0];   // [1,B,H]
    const float* enc    = (const float*)d_in[1];   // [S,B,H]
    const float* W      = (const float*)d_in[2];   // [H,H]
    // d_in[3] = b_attn: cancels in softmax (and is zero in setup_inputs)
    float* out = (float*)d_out;                    // [B,1,S]

    unsigned* ctrl = (unsigned*)d_ws;              // 64 words: bars/max/sum
    float*    v    = (float*)d_ws + 64;            // 16384 floats
    float* partial = v + BB * HH;                  // fallback scratch (1 MB)

    // zero barriers + maxbits + sums each call
    hipMemsetAsync(ctrl, 0, 64 * sizeof(unsigned), stream);

    // capability check (capture-safe queries; R3 lesson: verify the launch)
    int dev = 0;
    hipGetDevice(&dev);
    int numCU = 0;
    hipDeviceGetAttribute(&numCU, hipDeviceAttributeMultiprocessorCount, dev);
    int maxBlk = 0;
    hipError_t qe = hipOccupancyMaxActiveBlocksPerMultiprocessor(
        &maxBlk, (const void*)fused_kernel, BNT, 0);

    hipError_t le = hipErrorUnknown;
    if (qe == hipSuccess && maxBlk >= 2 && (long)maxBlk * numCU >= BNB) {
        le = hipSuccess;
        hipLaunchKernelGGL(fused_kernel, dim3(BNB), dim3(BNT), 0, stream,
                           hidden, enc, W, out, ctrl, v);
    }
    if (le != hipSuccess) {
        hipLaunchKernelGGL(gemv_partial_kernel, dim3(KC * 64), dim3(256), 0,
                           stream, hidden, W, partial);
        hipLaunchKernelGGL(gemv_reduce_kernel, dim3(BB * HH / 256), dim3(256),
                           0, stream, partial, v);
        hipLaunchKernelGGL(energies_kernel, dim3(BNB), dim3(BNT), 0, stream,
                           enc, v, out);
        hipLaunchKernelGGL(softmax_kernel, dim3(BB), dim3(256), 0, stream, out);
    }
}

// Round 10
// 59.272 us; speedup vs baseline: 1.0406x; 1.0406x over previous
//
#include <hip/hip_runtime.h>
#include <math.h>

// Problem: S=4096, B=16, H=1024
//   energies[b,s] = hidden[b,:] . (W @ enc[s,b,:] + b_attn)
//   out[b,0,s]    = softmax_s(energies[b,s])
// Reassociated: energies[b,s] = v[b,:] . enc[s,b,:] (+ const_b, cancels under
// softmax shift-invariance), v = hidden @ W.  b_attn never read.
//
// Refuted: coop-API fusion (R4, spills); spin-barrier fusion (R9, ~4us per
// device barrier + profiling pathology); nontemporal (R2); B@64-VGPR-cap
// (R6); low-wave GEMV (R8). B pinned at ~5.5-6 TB/s streaming-read wall
// across 3 structures (R5/R7/R9-P2).
// R10: R7 with A1+A2 merged into one atomic-GEMV dispatch (+64KB memset):
//   memset v (64 KB)                                   ~dispatch only
//   A : split-k GEMV, atomicAdd -> v (1024 blk, 4096 waves)  ~2.5 us
//   B : persistent contiguous stream, v in LDS (R7)    ~43-47 us (wall)
//   C : per-b softmax in-place on d_out (R7)           ~2.5 us

#define SS 4096
#define BB 16
#define HH 1024
#define KC 16          // k-chunks for split-k GEMV
#define KLEN (HH / KC) // 64

#define BNB 512        // kernel B: blocks (2 per CU, LDS-capped)
#define BNT 512        // kernel B: threads per block (8 waves)
#define NGRP (SS * BB / 32)   // 2048 groups of 32 consecutive pairs
#define TILES (NGRP / BNB)    // 4 groups per block

typedef float f4 __attribute__((ext_vector_type(4)));

// ---- A: v[b*HH+h] += sum_{k in chunk kc} hidden[b,k] * W[k,h] -------------
// 1024 blocks x 256 threads = 4096 waves (proven A1 shape). Block ->
// (kc, b, h-chunk of 256): W reads coalesced over h (1 KB/inst); hidden[b,k]
// wave-uniform. v pre-zeroed by memsetAsync; fp-atomic order noise ~1 ulp.
__global__ void __launch_bounds__(256)
gemv_atomic_kernel(const float* __restrict__ hidden,
                   const float* __restrict__ W,
                   float* __restrict__ v) {
    int blk = blockIdx.x;          // 0..1023
    int kc  = blk >> 6;            // 16 chunks
    int rb  = blk & 63;            // b(16) x hchunk(4)
    int b   = rb >> 2;
    int h   = ((rb & 3) << 8) | threadIdx.x;
    const float* hrow = hidden + b * HH + kc * KLEN;
    const float* Wp   = W + (size_t)(kc * KLEN) * HH + h;
    float a0 = 0.f, a1 = 0.f, a2 = 0.f, a3 = 0.f;
    #pragma unroll 4
    for (int k = 0; k < KLEN; k += 4) {
        a0 += hrow[k + 0] * Wp[(k + 0) * HH];
        a1 += hrow[k + 1] * Wp[(k + 1) * HH];
        a2 += hrow[k + 2] * Wp[(k + 2) * HH];
        a3 += hrow[k + 3] * Wp[(k + 3) * HH];
    }
    atomicAdd(&v[b * HH + h], (a0 + a1) + (a2 + a3));
}

// ---- B: energies[b,s] = v[b,:] . enc[s,b,:]  (persistent + contiguous) ----
// (unchanged from R7 — at the streaming-read wall)
// 512 blocks x 512 threads, 2 blocks/CU (LDS 64 KB/block). Each block stages
// the whole v (64 KB) into LDS once, then sweeps TILES=4 groups of 32
// CONSECUTIVE pairs p = s*16+b; wave i takes pairs p0=g*32+i*4..+3, i.e. one
// contiguous 16 KB span of enc per wave per tile. vv comes from LDS per pair.
// Butterfly-reduce, lane0 writes 4 floats.
__global__ void __launch_bounds__(BNT, 4)
energies_kernel(const float* __restrict__ enc,
                const float* __restrict__ v,
                float* __restrict__ out) {
    __shared__ f4 vlds[BB * HH / 4];        // 4096 f4 = 64 KB
    int tid = threadIdx.x;
    const f4* vg = (const f4*)v;
    #pragma unroll
    for (int it = 0; it < (BB * HH / 4) / BNT; ++it)   // 8 iters
        vlds[it * BNT + tid] = vg[it * BNT + tid];
    __syncthreads();

    int lane = tid & 63;
    int wi   = tid >> 6;                    // wave in block, 0..7
    for (int t = 0; t < TILES; ++t) {
        int g  = t * BNB + blockIdx.x;      // group 0..2047
        int p0 = g * 32 + wi * 4;           // first of 4 consecutive pairs
        float acc[4];
        #pragma unroll
        for (int j = 0; j < 4; ++j) {
            int p = p0 + j;
            int b = p & (BB - 1);
            const f4* e4 = (const f4*)(enc + (size_t)p * HH);
            f4 a0 = e4[0 * 64 + lane];
            f4 a1 = e4[1 * 64 + lane];
            f4 a2 = e4[2 * 64 + lane];
            f4 a3 = e4[3 * 64 + lane];
            f4 w0 = vlds[b * 256 + 0 * 64 + lane];
            f4 w1 = vlds[b * 256 + 1 * 64 + lane];
            f4 w2 = vlds[b * 256 + 2 * 64 + lane];
            f4 w3 = vlds[b * 256 + 3 * 64 + lane];
            f4 pr = a0 * w0 + a1 * w1 + a2 * w2 + a3 * w3;
            acc[j] = (pr.x + pr.y) + (pr.z + pr.w);
        }
        #pragma unroll
        for (int j = 0; j < 4; ++j) {
            #pragma unroll
            for (int off = 32; off; off >>= 1)
                acc[j] += __shfl_xor(acc[j], off, 64);
        }
        if (lane == 0) {
            #pragma unroll
            for (int j = 0; j < 4; ++j) {
                int p = p0 + j;
                out[(p & (BB - 1)) * SS + (p >> 4)] = acc[j];
            }
        }
    }
}

// ---- C: in-place softmax over s, one 256-thread block per b (unchanged) ---
__global__ void __launch_bounds__(256)
softmax_kernel(float* __restrict__ out) {
    int b = blockIdx.x;
    float* row = out + b * SS;
    int t = threadIdx.x;                 // 16 values per thread
    float vals[16];
    float m = -INFINITY;
    #pragma unroll
    for (int i = 0; i < 16; ++i) {
        vals[i] = row[t + i * 256];
        m = fmaxf(m, vals[i]);
    }
    #pragma unroll
    for (int off = 32; off; off >>= 1) m = fmaxf(m, __shfl_xor(m, off, 64));
    __shared__ float redm[4];
    __shared__ float reds[4];
    int wid = t >> 6;
    if ((t & 63) == 0) redm[wid] = m;
    __syncthreads();
    m = fmaxf(fmaxf(redm[0], redm[1]), fmaxf(redm[2], redm[3]));

    float sum = 0.f;
    #pragma unroll
    for (int i = 0; i < 16; ++i) {
        vals[i] = expf(vals[i] - m);
        sum += vals[i];
    }
    #pragma unroll
    for (int off = 32; off; off >>= 1) sum += __shfl_xor(sum, off, 64);
    if ((t & 63) == 0) reds[wid] = sum;
    __syncthreads();
    sum = reds[0] + reds[1] + reds[2] + reds[3];
    float inv = 1.0f / sum;
    #pragma unroll
    for (int i = 0; i < 16; ++i) row[t + i * 256] = vals[i] * inv;
}

extern "C" void kernel_launch(void* const* d_in, const int* in_sizes, int n_in,
                              void* d_out, int out_size, void* d_ws, size_t ws_size,
                              hipStream_t stream) {
    const float* hidden = (const float*)d_in[0];   // [1,B,H]
    const float* enc    = (const float*)d_in[1];   // [S,B,H]
    const float* W      = (const float*)d_in[2];   // [H,H]
    // d_in[3] = b_attn: cancels in softmax (and is zero in setup_inputs)
    float* out = (float*)d_out;                    // [B,1,S]
    float* v   = (float*)d_ws;                     // B*H floats = 64 KB

    hipMemsetAsync(v, 0, BB * HH * sizeof(float), stream);
    hipLaunchKernelGGL(gemv_atomic_kernel, dim3(KC * 64), dim3(256), 0, stream,
                       hidden, W, v);
    hipLaunchKernelGGL(energies_kernel, dim3(BNB), dim3(BNT), 0, stream,
                       enc, v, out);
    hipLaunchKernelGGL(softmax_kernel, dim3(BB), dim3(256), 0, stream, out);
}